// Round 7
// baseline (651.580 us; speedup 1.0000x reference)
//
#include <hip/hip_runtime.h>
#include <hip/hip_bf16.h>
#include <stdint.h>

// Problem constants
#define BATCH   8192
#define IN_DIM  1024
#define N_HID   2048
#define OUT_DIM 256
#define SRC_DIM 3072

// Tiling
#define C     32                   // source columns per chunk
#define RB    32                   // rows per row-block (= rows per wave)
#define BT    128                  // batch per block (2 per lane: b, b+64)
#define S1_CH (IN_DIM / C)         // 32
#define S1_RB (N_HID / RB)         // 64
#define S2_CH (SRC_DIM / C)        // 96
#define S2_RB (OUT_DIM / RB)       // 8
#define NSEG1 (S1_RB * S1_CH)      // 2048
#define NSEG2 (S2_RB * S2_CH)      // 768
#define MAXW  8                    // max 4-slot planes per row (n<=32)
#define SEG_U32 (MAXW * RB)        // 256 u32 per segment
#define ZSLOT 128                  // A-tile zero page (pad byte 0x80)

// MEASURED MODEL (R3/R5/R6): effective LDS pool ~96 KB/CU for residency:
// 41.5KB->2 blocks, 50.2KB->1 block, 21.5KB->4 blocks. R3 = LDS-issue floor
// (34.4M ds_read_b32 x 5.8cyc/256CU = 325us ~ measured 318). So: halve LDS
// instrs (K=2 bf16-pair) and keep LDS/block = A-tile only (33KB -> 2 blocks)
// by reading activations straight from x_t/hidden_t (col-major, coalesced).

// ---------------------------------------------------------------------------
// k_prep (R5-proven): one wave per (row-block, chunk); plane-major 4-slot u32
// records, slot byte = t*32+c, pad 0x80. hdr = plane count W.
// ---------------------------------------------------------------------------
__global__ void k_prep(const int* __restrict__ mat,
                       uint32_t* __restrict__ seg1, uint32_t* __restrict__ seg2,
                       uint32_t* __restrict__ hdr1, uint32_t* __restrict__ hdr2) {
    int wid  = (blockIdx.x * blockDim.x + threadIdx.x) >> 6;
    int lane = threadIdx.x & 63;
    if (wid >= NSEG1 + NSEG2) return;

    int row0, col0;
    uint32_t *seg, *hdr;
    if (wid < NSEG1) {
        int rb = wid / S1_CH, ch = wid % S1_CH;
        row0 = rb * RB;          col0 = ch * C;
        seg = seg1 + (size_t)wid * SEG_U32;  hdr = hdr1 + wid;
    } else {
        int s  = wid - NSEG1;
        int rb = s / S2_CH, ch = s % S2_CH;
        row0 = N_HID + rb * RB;  col0 = ch * C;
        seg = seg2 + (size_t)s * SEG_U32;    hdr = hdr2 + s;
    }

    int n = 0;
    if (lane < RB) {
        const int* mrow = mat + (size_t)(row0 + lane) * SRC_DIM + col0;
        uint8_t* sb = (uint8_t*)seg;
        for (int c = 0; c < C; c++) {
            int code = mrow[c];
            if (code != 0) {
                sb[(size_t)(n >> 2) * (RB * 4) + lane * 4 + (n & 3)] =
                    (uint8_t)((code - 1) * C + c);
                n++;
            }
        }
    }
    int m = n;
    #pragma unroll
    for (int d = 1; d < 64; d <<= 1) m = max(m, __shfl_xor(m, d));
    if (lane == 0) *hdr = (uint32_t)((m + 3) >> 2);
}

// ---------------------------------------------------------------------------
// k_xt: transpose x[8192][1024] -> x_t[1024][8192] (fp32), 64x64 LDS tiles.
// ---------------------------------------------------------------------------
__global__ __launch_bounds__(256) void k_xt(const float* __restrict__ x,
                                            float* __restrict__ x_t) {
    __shared__ float t[64][65];
    const int b0 = blockIdx.x * 64, c0 = blockIdx.y * 64;
    {
        int r  = threadIdx.x >> 4;
        int cq = (threadIdx.x & 15) * 4;
        #pragma unroll
        for (int k = 0; k < 4; k++) {
            int rr = r + 16 * k;
            float4 v = *(const float4*)&x[(size_t)(b0 + rr) * IN_DIM + c0 + cq];
            t[rr][cq + 0] = v.x; t[rr][cq + 1] = v.y;
            t[rr][cq + 2] = v.z; t[rr][cq + 3] = v.w;
        }
    }
    __syncthreads();
    {
        int bq  = (threadIdx.x & 15) * 4;
        int cc0 = threadIdx.x >> 4;
        #pragma unroll
        for (int k = 0; k < 4; k++) {
            int cc = cc0 + 16 * k;
            float4 v;
            v.x = t[bq + 0][cc]; v.y = t[bq + 1][cc];
            v.z = t[bq + 2][cc]; v.w = t[bq + 3][cc];
            *(float4*)&x_t[(size_t)(c0 + cc) * BATCH + b0 + bq] = v;
        }
    }
}

// pack two floats as bf16 pair: low16 = batch b, high16 = batch b+64
__device__ __forceinline__ uint32_t pack2(float a, float b) {
    __hip_bfloat162 h = __float22bfloat162_rn(make_float2(a, b));
    union { __hip_bfloat162 h2; uint32_t u; } u;
    u.h2 = h;
    return u.u;
}

// A-tile: As[slot*64 + lane] u32 = bf16 pair; slot = t*32+c; slot 128 = zeros.
__device__ __forceinline__ void write_acts2(uint32_t* As, int c, int lane,
                                            float va, float vb) {
    As[(0 * C + c) * 64 + lane] = pack2(va, vb);
    As[(1 * C + c) * 64 + lane] = pack2(fmaxf(va, 0.0f), fmaxf(vb, 0.0f));
    float ta = 1.0f - 2.0f / (__expf(2.0f * va) + 1.0f);
    float tb = 1.0f - 2.0f / (__expf(2.0f * vb) + 1.0f);
    As[(2 * C + c) * 64 + lane] = pack2(ta, tb);
    float sa = 1.0f / (1.0f + __expf(-va));
    float sb = 1.0f / (1.0f + __expf(-vb));
    As[(3 * C + c) * 64 + lane] = pack2(sa, sb);
}

#define ACC_ROW_BODY(G)                                                        \
    {                                                                          \
        uint32_t q0 = As[((G) & 255u) * 64 + lane];                            \
        uint32_t q1 = As[(((G) >> 8) & 255u) * 64 + lane];                     \
        uint32_t q2 = As[(((G) >> 16) & 255u) * 64 + lane];                    \
        uint32_t q3 = As[((G) >> 24) * 64 + lane];                             \
        xa += __uint_as_float(q0 << 16); xb += __uint_as_float(q0 & 0xFFFF0000u); \
        xa += __uint_as_float(q1 << 16); xb += __uint_as_float(q1 & 0xFFFF0000u); \
        xa += __uint_as_float(q2 << 16); xb += __uint_as_float(q2 & 0xFFFF0000u); \
        xa += __uint_as_float(q3 << 16); xb += __uint_as_float(q3 & 0xFFFF0000u); \
    }

#define EDGE_PLANES(SEGBASE, WVAL)                                             \
    {                                                                          \
        const uint32_t* rec_ = (SEGBASE);                                      \
        _Pragma("unroll")                                                      \
        for (int r = 0; r < RB; r++) {                                         \
            uint32_t g = rec_[r];                                              \
            float xa = accA[r], xb = accB[r];                                  \
            ACC_ROW_BODY(g)                                                    \
            accA[r] = xa; accB[r] = xb;                                        \
        }                                                                      \
        for (uint32_t p = 1; p < (WVAL); p++) {                                \
            const uint32_t* rp_ = rec_ + p * RB;                               \
            _Pragma("unroll")                                                  \
            for (int r = 0; r < RB; r++) {                                     \
                uint32_t g = rp_[r];                                           \
                if (g != 0x80808080u) {                                        \
                    float xa = accA[r], xb = accB[r];                          \
                    ACC_ROW_BODY(g)                                            \
                    accA[r] = xa; accB[r] = xb;                                \
                }                                                              \
            }                                                                  \
        }                                                                      \
    }

// ---------------------------------------------------------------------------
// Stage 1: 512 thr = 8 waves x 32 rows; lane pair = batch (b, b+64).
// Grid (64 tiles, 8 row splits). LDS = A-tile only (33.0 KB -> 2 blocks/CU).
// Activations read from x_t (coalesced), prefetched one chunk ahead.
// ---------------------------------------------------------------------------
__global__ __launch_bounds__(512, 2) void k_hid(const float* __restrict__ x_t,
                                                const float* __restrict__ wp,
                                                const uint32_t* __restrict__ seg1,
                                                const uint32_t* __restrict__ hdr1,
                                                __hip_bfloat16* __restrict__ hidden_t) {
    __shared__ uint32_t As[(4 * C + 1) * 64];   // 33.0 KB

    const float w  = wp[0];
    const int tile = blockIdx.x;                // 0..63
    const int lane = threadIdx.x & 63;
    const int wv   = __builtin_amdgcn_readfirstlane(threadIdx.x >> 6); // 0..7
    const int rb   = blockIdx.y * 8 + wv;       // 0..63
    const int bA   = tile * BT + lane;
    const int bB   = bA + 64;

    if (threadIdx.x < 64) As[ZSLOT * 64 + threadIdx.x] = 0u;

    float accA[RB], accB[RB];
    #pragma unroll
    for (int r = 0; r < RB; r++) { accA[r] = 0.0f; accB[r] = 0.0f; }

    // prefetch chunk 0 activations inputs
    float va[4], vb[4];
    #pragma unroll
    for (int j = 0; j < 4; j++) {
        int gcol = wv * 4 + j;
        va[j] = w * x_t[(size_t)gcol * BATCH + bA];
        vb[j] = w * x_t[(size_t)gcol * BATCH + bB];
    }

    #pragma unroll 1
    for (int ch = 0; ch < S1_CH; ch++) {
        __syncthreads();                        // edge-phase(ch-1) done
        #pragma unroll
        for (int j = 0; j < 4; j++)
            write_acts2(As, wv * 4 + j, lane, va[j], vb[j]);
        __syncthreads();                        // acts visible
        if (ch + 1 < S1_CH) {                   // prefetch next chunk (long runway)
            #pragma unroll
            for (int j = 0; j < 4; j++) {
                int gcol = (ch + 1) * C + wv * 4 + j;
                va[j] = w * x_t[(size_t)gcol * BATCH + bA];
                vb[j] = w * x_t[(size_t)gcol * BATCH + bB];
            }
        }
        int sidx = rb * S1_CH + ch;
        uint32_t W = hdr1[sidx];
        EDGE_PLANES(seg1 + (size_t)sidx * SEG_U32, W)
    }

    const int row0 = rb * RB;
    #pragma unroll
    for (int r = 0; r < RB; r++) {
        hidden_t[(size_t)(row0 + r) * BATCH + bA] = __float2bfloat16(accA[r]);
        hidden_t[(size_t)(row0 + r) * BATCH + bB] = __float2bfloat16(accB[r]);
    }
}

// ---------------------------------------------------------------------------
// Stage 2: 256 thr = 4 waves x 32 rows. Grid (64 tiles, 8): y = rsplit(2) x
// cg(4), 24 chunks per cg. LDS = A-tile only -> 2 blocks/CU.
// ---------------------------------------------------------------------------
__global__ __launch_bounds__(256, 2) void k_out(const float* __restrict__ x_t,
                                                const __hip_bfloat16* __restrict__ hidden_t,
                                                const float* __restrict__ wp,
                                                const uint32_t* __restrict__ seg2,
                                                const uint32_t* __restrict__ hdr2,
                                                float* __restrict__ partials) {
    __shared__ uint32_t As[(4 * C + 1) * 64];

    const float w  = wp[0];
    const int tile   = blockIdx.x;              // 0..63
    const int rsplit = blockIdx.y & 1;          // 0..1
    const int cg     = blockIdx.y >> 1;         // 0..3
    const int lane = threadIdx.x & 63;
    const int wv   = __builtin_amdgcn_readfirstlane(threadIdx.x >> 6); // 0..3
    const int rbk  = rsplit * 4 + wv;           // row-block 0..7
    const int bA   = tile * BT + lane;
    const int bB   = bA + 64;

    if (threadIdx.x < 64) As[ZSLOT * 64 + threadIdx.x] = 0u;

    float accA[RB], accB[RB];
    #pragma unroll
    for (int r = 0; r < RB; r++) { accA[r] = 0.0f; accB[r] = 0.0f; }

    // each wave owns 8 cols; prefetch chunk cg*24
    float va[8], vb[8];
    #pragma unroll
    for (int j = 0; j < 8; j++) {
        int gcol = (cg * 24) * C + wv * 8 + j;
        if (gcol < IN_DIM) {
            va[j] = w * x_t[(size_t)gcol * BATCH + bA];
            vb[j] = w * x_t[(size_t)gcol * BATCH + bB];
        } else {
            va[j] = w * __bfloat162float(hidden_t[(size_t)(gcol - IN_DIM) * BATCH + bA]);
            vb[j] = w * __bfloat162float(hidden_t[(size_t)(gcol - IN_DIM) * BATCH + bB]);
        }
    }

    #pragma unroll 1
    for (int cj = 0; cj < 24; cj++) {
        int ch = cg * 24 + cj;
        __syncthreads();
        #pragma unroll
        for (int j = 0; j < 8; j++)
            write_acts2(As, wv * 8 + j, lane, va[j], vb[j]);
        __syncthreads();
        if (cj + 1 < 24) {
            #pragma unroll
            for (int j = 0; j < 8; j++) {
                int gcol = (ch + 1) * C + wv * 8 + j;
                if (gcol < IN_DIM) {
                    va[j] = w * x_t[(size_t)gcol * BATCH + bA];
                    vb[j] = w * x_t[(size_t)gcol * BATCH + bB];
                } else {
                    va[j] = w * __bfloat162float(hidden_t[(size_t)(gcol - IN_DIM) * BATCH + bA]);
                    vb[j] = w * __bfloat162float(hidden_t[(size_t)(gcol - IN_DIM) * BATCH + bB]);
                }
            }
        }
        int sidx = rbk * S2_CH + ch;
        uint32_t W = hdr2[sidx];
        EDGE_PLANES(seg2 + (size_t)sidx * SEG_U32, W)
    }

    #pragma unroll
    for (int r = 0; r < RB; r++) {
        size_t base = ((size_t)cg * OUT_DIM + rbk * RB + r) * BATCH;
        partials[base + bA] = accA[r];
        partials[base + bB] = accB[r];
    }
}

// ---------------------------------------------------------------------------
// k_sum: reduce 4 partial planes + transpose [r][b] -> out[b][r] (float4).
// ---------------------------------------------------------------------------
__global__ __launch_bounds__(256) void k_sum(const float* __restrict__ partials,
                                             float* __restrict__ out) {
    __shared__ float t[16][65];
    const int b0 = blockIdx.x * 64, r0 = blockIdx.y * 16;
    const int lane = threadIdx.x & 63;
    const int g4   = threadIdx.x >> 6;

    #pragma unroll
    for (int k = 0; k < 4; k++) {
        int rr = g4 * 4 + k;
        float s = 0.0f;
        #pragma unroll
        for (int cg = 0; cg < 4; cg++)
            s += partials[((size_t)cg * OUT_DIM + r0 + rr) * BATCH + b0 + lane];
        t[rr][lane] = s;
    }
    __syncthreads();
    int bb = threadIdx.x >> 2, rq = threadIdx.x & 3;
    float4 v;
    v.x = t[rq * 4 + 0][bb];
    v.y = t[rq * 4 + 1][bb];
    v.z = t[rq * 4 + 2][bb];
    v.w = t[rq * 4 + 3][bb];
    *(float4*)&out[(size_t)(b0 + bb) * OUT_DIM + r0 + rq * 4] = v;
}

// ---------------------------------------------------------------------------
extern "C" void kernel_launch(void* const* d_in, const int* in_sizes, int n_in,
                              void* d_out, int out_size, void* d_ws, size_t ws_size,
                              hipStream_t stream) {
    const float* x   = (const float*)d_in[0];
    const float* w   = (const float*)d_in[1];
    const int*   mat = (const int*)d_in[2];
    float* out = (float*)d_out;

    uint8_t* ws = (uint8_t*)d_ws;
    size_t off = 0;
    __hip_bfloat16* hidden_t = (__hip_bfloat16*)(ws + off); off += (size_t)BATCH * N_HID * 2;  // 33.6 MB
    float* x_t = (float*)(ws + off);        off += (size_t)IN_DIM * BATCH * 4;                 // 33.6 MB
    uint32_t* seg1 = (uint32_t*)(ws + off); off += (size_t)NSEG1 * SEG_U32 * 4;                //  2.10 MB
    uint32_t* seg2 = (uint32_t*)(ws + off); off += (size_t)NSEG2 * SEG_U32 * 4;                //  0.79 MB
    uint32_t* hdr1 = (uint32_t*)(ws + off); off += (size_t)NSEG1 * 4;
    uint32_t* hdr2 = (uint32_t*)(ws + off); off += (size_t)NSEG2 * 4;
    float* partials = (float*)(ws + off);   off += (size_t)4 * OUT_DIM * BATCH * 4;            // 33.6 MB
    (void)ws_size; (void)in_sizes; (void)n_in; (void)out_size;

    hipMemsetAsync(seg1, 0x80, (size_t)(NSEG1 + NSEG2) * SEG_U32 * 4, stream);

    {
        int nseg = NSEG1 + NSEG2;
        k_prep<<<(nseg + 3) / 4, 256, 0, stream>>>(mat, seg1, seg2, hdr1, hdr2);
    }
    {
        dim3 g(BATCH / 64, IN_DIM / 64);            // 128 x 16
        k_xt<<<g, 256, 0, stream>>>(x, x_t);
    }
    {
        dim3 g(BATCH / BT, 8);                      // 64 x 8 = 512 blocks
        k_hid<<<g, 512, 0, stream>>>(x_t, w, seg1, hdr1, hidden_t);
    }
    {
        dim3 g(BATCH / BT, 8);                      // 64 x 8 = 512 blocks
        k_out<<<g, 256, 0, stream>>>(x_t, hidden_t, w, seg2, hdr2, partials);
    }
    {
        dim3 g(BATCH / 64, OUT_DIM / 16);           // 2048 blocks
        k_sum<<<g, 256, 0, stream>>>(partials, out);
    }
}

// Round 8
// 506.392 us; speedup vs baseline: 1.2867x; 1.2867x over previous
//
#include <hip/hip_runtime.h>
#include <hip/hip_bf16.h>
#include <stdint.h>

// Problem constants
#define BATCH   8192
#define IN_DIM  1024
#define N_HID   2048
#define OUT_DIM 256
#define SRC_DIM 3072

// Tiling
#define C     32                   // source columns per chunk
#define RB    16                   // rows per row-block (= rows per wave)
#define BT    128                  // batch per block (2 per lane: b, b+64)
#define S1_CH (IN_DIM / C)         // 32
#define S1_RB (N_HID / RB)         // 128
#define S2_CH (SRC_DIM / C)        // 96
#define S2_RB (OUT_DIM / RB)       // 16
#define NSEG1 (S1_RB * S1_CH)      // 4096
#define NSEG2 (S2_RB * S2_CH)      // 1536
#define MAXW  8                    // planes per segment (4-slot u32 per row)
#define SEG_U32 (MAXW * RB)        // 128 u32 per segment
#define ZSLOT 128                  // A-tile zero page (pad byte 0x80)

// MEASURED MODEL (R3..R7): residency does NOT follow a simple LDS-pool rule
// (R7: 33KB/512thr/VGPR108 -> only 8 waves/CU). It tracks total register
// footprint (unified VGPR/AGPR). Insurance: ONE 1024-thr block = 16 waves
// sharing one 33KB A-tile -> 4 waves/SIMD guaranteed whenever the block
// launches. Keep VGPR low (RB=16 -> 32 accs).

// ---------------------------------------------------------------------------
// k_prep: one wave per (row-block, chunk) segment; lane r (<16) scans its
// row's 32 codes into plane-major 4-slot u32 records; slot byte = t*32+c,
// pad 0x80 (from memset). hdr = plane count W = ceil(max_n/4).
// ---------------------------------------------------------------------------
__global__ void k_prep(const int* __restrict__ mat,
                       uint32_t* __restrict__ seg1, uint32_t* __restrict__ seg2,
                       uint32_t* __restrict__ hdr1, uint32_t* __restrict__ hdr2) {
    int wid  = (blockIdx.x * blockDim.x + threadIdx.x) >> 6;
    int lane = threadIdx.x & 63;
    if (wid >= NSEG1 + NSEG2) return;

    int row0, col0;
    uint32_t *seg, *hdr;
    if (wid < NSEG1) {
        int rb = wid / S1_CH, ch = wid % S1_CH;
        row0 = rb * RB;          col0 = ch * C;
        seg = seg1 + (size_t)wid * SEG_U32;  hdr = hdr1 + wid;
    } else {
        int s  = wid - NSEG1;
        int rb = s / S2_CH, ch = s % S2_CH;
        row0 = N_HID + rb * RB;  col0 = ch * C;
        seg = seg2 + (size_t)s * SEG_U32;    hdr = hdr2 + s;
    }

    int n = 0;
    if (lane < RB) {
        const int* mrow = mat + (size_t)(row0 + lane) * SRC_DIM + col0;
        uint8_t* sb = (uint8_t*)seg;
        for (int c = 0; c < C; c++) {
            int code = mrow[c];
            if (code != 0) {
                sb[(size_t)(n >> 2) * (RB * 4) + lane * 4 + (n & 3)] =
                    (uint8_t)((code - 1) * C + c);
                n++;
            }
        }
    }
    int m = n;
    #pragma unroll
    for (int d = 1; d < 64; d <<= 1) m = max(m, __shfl_xor(m, d));
    if (lane == 0) *hdr = (uint32_t)((m + 3) >> 2);
}

// ---------------------------------------------------------------------------
// k_xt: transpose x[8192][1024] -> x_t[1024][8192] (fp32), 64x64 LDS tiles.
// ---------------------------------------------------------------------------
__global__ __launch_bounds__(256) void k_xt(const float* __restrict__ x,
                                            float* __restrict__ x_t) {
    __shared__ float t[64][65];
    const int b0 = blockIdx.x * 64, c0 = blockIdx.y * 64;
    {
        int r  = threadIdx.x >> 4;
        int cq = (threadIdx.x & 15) * 4;
        #pragma unroll
        for (int k = 0; k < 4; k++) {
            int rr = r + 16 * k;
            float4 v = *(const float4*)&x[(size_t)(b0 + rr) * IN_DIM + c0 + cq];
            t[rr][cq + 0] = v.x; t[rr][cq + 1] = v.y;
            t[rr][cq + 2] = v.z; t[rr][cq + 3] = v.w;
        }
    }
    __syncthreads();
    {
        int bq  = (threadIdx.x & 15) * 4;
        int cc0 = threadIdx.x >> 4;
        #pragma unroll
        for (int k = 0; k < 4; k++) {
            int cc = cc0 + 16 * k;
            float4 v;
            v.x = t[bq + 0][cc]; v.y = t[bq + 1][cc];
            v.z = t[bq + 2][cc]; v.w = t[bq + 3][cc];
            *(float4*)&x_t[(size_t)(c0 + cc) * BATCH + b0 + bq] = v;
        }
    }
}

// pack two floats as bf16 pair: low16 = batch b, high16 = batch b+64
__device__ __forceinline__ uint32_t pack2(float a, float b) {
    __hip_bfloat162 h = __float22bfloat162_rn(make_float2(a, b));
    union { __hip_bfloat162 h2; uint32_t u; } u;
    u.h2 = h;
    return u.u;
}

// A-tile: As[slot*64 + lane] u32 = bf16 pair; slot = t*32+c; slot 128 = zeros.
__device__ __forceinline__ void write_acts2(uint32_t* As, int c, int lane,
                                            float va, float vb) {
    As[(0 * C + c) * 64 + lane] = pack2(va, vb);
    As[(1 * C + c) * 64 + lane] = pack2(fmaxf(va, 0.0f), fmaxf(vb, 0.0f));
    float ta = 1.0f - 2.0f / (__expf(2.0f * va) + 1.0f);
    float tb = 1.0f - 2.0f / (__expf(2.0f * vb) + 1.0f);
    As[(2 * C + c) * 64 + lane] = pack2(ta, tb);
    float sa = 1.0f / (1.0f + __expf(-va));
    float sb = 1.0f / (1.0f + __expf(-vb));
    As[(3 * C + c) * 64 + lane] = pack2(sa, sb);
}

#define ACC_ROW_BODY(G)                                                        \
    {                                                                          \
        uint32_t q0 = As[((G) & 255u) * 64 + lane];                            \
        uint32_t q1 = As[(((G) >> 8) & 255u) * 64 + lane];                     \
        uint32_t q2 = As[(((G) >> 16) & 255u) * 64 + lane];                    \
        uint32_t q3 = As[((G) >> 24) * 64 + lane];                             \
        xa += __uint_as_float(q0 << 16); xb += __uint_as_float(q0 & 0xFFFF0000u); \
        xa += __uint_as_float(q1 << 16); xb += __uint_as_float(q1 & 0xFFFF0000u); \
        xa += __uint_as_float(q2 << 16); xb += __uint_as_float(q2 & 0xFFFF0000u); \
        xa += __uint_as_float(q3 << 16); xb += __uint_as_float(q3 & 0xFFFF0000u); \
    }

#define EDGE_PLANES(SEGBASE, WVAL)                                             \
    {                                                                          \
        const uint32_t* rec_ = (SEGBASE);                                      \
        _Pragma("unroll")                                                      \
        for (int r = 0; r < RB; r++) {                                         \
            uint32_t g = rec_[r];                                              \
            float xa = accA[r], xb = accB[r];                                  \
            ACC_ROW_BODY(g)                                                    \
            accA[r] = xa; accB[r] = xb;                                        \
        }                                                                      \
        for (uint32_t p = 1; p < (WVAL); p++) {                                \
            const uint32_t* rp_ = rec_ + p * RB;                               \
            _Pragma("unroll")                                                  \
            for (int r = 0; r < RB; r++) {                                     \
                uint32_t g = rp_[r];                                           \
                if (g != 0x80808080u) {                                        \
                    float xa = accA[r], xb = accB[r];                          \
                    ACC_ROW_BODY(g)                                            \
                    accA[r] = xa; accB[r] = xb;                                \
                }                                                              \
            }                                                                  \
        }                                                                      \
    }

// ---------------------------------------------------------------------------
// Stage 1: 1024 thr = 16 waves x 16 rows = 256 rows; lane pair = (b, b+64).
// Grid (64 tiles, 8 row splits) = 512 blocks. LDS = A-tile only (33.25 KB).
// One resident block = 16 waves/CU = 4/SIMD guaranteed.
// ---------------------------------------------------------------------------
__global__ __launch_bounds__(1024, 1) void k_hid(const float* __restrict__ x_t,
                                                 const float* __restrict__ wp,
                                                 const uint32_t* __restrict__ seg1,
                                                 const uint32_t* __restrict__ hdr1,
                                                 __hip_bfloat16* __restrict__ hidden_t) {
    __shared__ uint32_t As[(4 * C + 1) * 64];   // 33.25 KB

    const float w  = wp[0];
    const int tile = blockIdx.x;                // 0..63
    const int lane = threadIdx.x & 63;
    const int wv   = __builtin_amdgcn_readfirstlane(threadIdx.x >> 6); // 0..15
    const int rb   = blockIdx.y * 16 + wv;      // row-block 0..127
    const int bA   = tile * BT + lane;
    const int bB   = bA + 64;

    if (threadIdx.x < 64) As[ZSLOT * 64 + threadIdx.x] = 0u;

    float accA[RB], accB[RB];
    #pragma unroll
    for (int r = 0; r < RB; r++) { accA[r] = 0.0f; accB[r] = 0.0f; }

    // prefetch chunk 0: each wave owns 2 columns
    float va[2], vb[2];
    #pragma unroll
    for (int j = 0; j < 2; j++) {
        int gcol = wv * 2 + j;
        va[j] = w * x_t[(size_t)gcol * BATCH + bA];
        vb[j] = w * x_t[(size_t)gcol * BATCH + bB];
    }

    #pragma unroll 1
    for (int ch = 0; ch < S1_CH; ch++) {
        __syncthreads();                        // edge-phase(ch-1) done
        #pragma unroll
        for (int j = 0; j < 2; j++)
            write_acts2(As, wv * 2 + j, lane, va[j], vb[j]);
        __syncthreads();                        // acts visible
        if (ch + 1 < S1_CH) {                   // prefetch next chunk
            #pragma unroll
            for (int j = 0; j < 2; j++) {
                int gcol = (ch + 1) * C + wv * 2 + j;
                va[j] = w * x_t[(size_t)gcol * BATCH + bA];
                vb[j] = w * x_t[(size_t)gcol * BATCH + bB];
            }
        }
        int sidx = rb * S1_CH + ch;
        uint32_t W = hdr1[sidx];
        EDGE_PLANES(seg1 + (size_t)sidx * SEG_U32, W)
    }

    const int row0 = rb * RB;
    #pragma unroll
    for (int r = 0; r < RB; r++) {
        hidden_t[(size_t)(row0 + r) * BATCH + bA] = __float2bfloat16(accA[r]);
        hidden_t[(size_t)(row0 + r) * BATCH + bB] = __float2bfloat16(accB[r]);
    }
}

// ---------------------------------------------------------------------------
// Stage 2: 1024 thr = 16 waves x 16 rows = ALL 256 out rows.
// Grid (64 tiles, 4 chunk groups of 24) = 256 blocks. Partials [cg][r][b].
// ---------------------------------------------------------------------------
__global__ __launch_bounds__(1024, 1) void k_out(const float* __restrict__ x_t,
                                                 const __hip_bfloat16* __restrict__ hidden_t,
                                                 const float* __restrict__ wp,
                                                 const uint32_t* __restrict__ seg2,
                                                 const uint32_t* __restrict__ hdr2,
                                                 float* __restrict__ partials) {
    __shared__ uint32_t As[(4 * C + 1) * 64];

    const float w  = wp[0];
    const int tile = blockIdx.x;                // 0..63
    const int cg   = blockIdx.y;                // 0..3
    const int lane = threadIdx.x & 63;
    const int wv   = __builtin_amdgcn_readfirstlane(threadIdx.x >> 6); // 0..15
    const int bA   = tile * BT + lane;
    const int bB   = bA + 64;

    if (threadIdx.x < 64) As[ZSLOT * 64 + threadIdx.x] = 0u;

    float accA[RB], accB[RB];
    #pragma unroll
    for (int r = 0; r < RB; r++) { accA[r] = 0.0f; accB[r] = 0.0f; }

    // prefetch chunk cg*24: each wave owns 2 columns
    float va[2], vb[2];
    #pragma unroll
    for (int j = 0; j < 2; j++) {
        int gcol = (cg * 24) * C + wv * 2 + j;
        if (gcol < IN_DIM) {
            va[j] = w * x_t[(size_t)gcol * BATCH + bA];
            vb[j] = w * x_t[(size_t)gcol * BATCH + bB];
        } else {
            va[j] = w * __bfloat162float(hidden_t[(size_t)(gcol - IN_DIM) * BATCH + bA]);
            vb[j] = w * __bfloat162float(hidden_t[(size_t)(gcol - IN_DIM) * BATCH + bB]);
        }
    }

    #pragma unroll 1
    for (int cj = 0; cj < 24; cj++) {
        int ch = cg * 24 + cj;
        __syncthreads();
        #pragma unroll
        for (int j = 0; j < 2; j++)
            write_acts2(As, wv * 2 + j, lane, va[j], vb[j]);
        __syncthreads();
        if (cj + 1 < 24) {
            #pragma unroll
            for (int j = 0; j < 2; j++) {
                int gcol = (ch + 1) * C + wv * 2 + j;
                if (gcol < IN_DIM) {
                    va[j] = w * x_t[(size_t)gcol * BATCH + bA];
                    vb[j] = w * x_t[(size_t)gcol * BATCH + bB];
                } else {
                    va[j] = w * __bfloat162float(hidden_t[(size_t)(gcol - IN_DIM) * BATCH + bA]);
                    vb[j] = w * __bfloat162float(hidden_t[(size_t)(gcol - IN_DIM) * BATCH + bB]);
                }
            }
        }
        int sidx = wv * S2_CH + ch;              // wv = row-block 0..15
        uint32_t W = hdr2[sidx];
        EDGE_PLANES(seg2 + (size_t)sidx * SEG_U32, W)
    }

    #pragma unroll
    for (int r = 0; r < RB; r++) {
        size_t base = ((size_t)cg * OUT_DIM + wv * RB + r) * BATCH;
        partials[base + bA] = accA[r];
        partials[base + bB] = accB[r];
    }
}

// ---------------------------------------------------------------------------
// k_sum: reduce 4 partial planes + transpose [r][b] -> out[b][r] (float4).
// ---------------------------------------------------------------------------
__global__ __launch_bounds__(256) void k_sum(const float* __restrict__ partials,
                                             float* __restrict__ out) {
    __shared__ float t[16][65];
    const int b0 = blockIdx.x * 64, r0 = blockIdx.y * 16;
    const int lane = threadIdx.x & 63;
    const int g4   = threadIdx.x >> 6;

    #pragma unroll
    for (int k = 0; k < 4; k++) {
        int rr = g4 * 4 + k;
        float s = 0.0f;
        #pragma unroll
        for (int cg = 0; cg < 4; cg++)
            s += partials[((size_t)cg * OUT_DIM + r0 + rr) * BATCH + b0 + lane];
        t[rr][lane] = s;
    }
    __syncthreads();
    int bb = threadIdx.x >> 2, rq = threadIdx.x & 3;
    float4 v;
    v.x = t[rq * 4 + 0][bb];
    v.y = t[rq * 4 + 1][bb];
    v.z = t[rq * 4 + 2][bb];
    v.w = t[rq * 4 + 3][bb];
    *(float4*)&out[(size_t)(b0 + bb) * OUT_DIM + r0 + rq * 4] = v;
}

// ---------------------------------------------------------------------------
extern "C" void kernel_launch(void* const* d_in, const int* in_sizes, int n_in,
                              void* d_out, int out_size, void* d_ws, size_t ws_size,
                              hipStream_t stream) {
    const float* x   = (const float*)d_in[0];
    const float* w   = (const float*)d_in[1];
    const int*   mat = (const int*)d_in[2];
    float* out = (float*)d_out;

    uint8_t* ws = (uint8_t*)d_ws;
    size_t off = 0;
    __hip_bfloat16* hidden_t = (__hip_bfloat16*)(ws + off); off += (size_t)BATCH * N_HID * 2;  // 33.6 MB
    float* x_t = (float*)(ws + off);        off += (size_t)IN_DIM * BATCH * 4;                 // 33.6 MB
    uint32_t* seg1 = (uint32_t*)(ws + off); off += (size_t)NSEG1 * SEG_U32 * 4;                //  2.10 MB
    uint32_t* seg2 = (uint32_t*)(ws + off); off += (size_t)NSEG2 * SEG_U32 * 4;                //  0.79 MB
    uint32_t* hdr1 = (uint32_t*)(ws + off); off += (size_t)NSEG1 * 4;
    uint32_t* hdr2 = (uint32_t*)(ws + off); off += (size_t)NSEG2 * 4;
    float* partials = (float*)(ws + off);   off += (size_t)4 * OUT_DIM * BATCH * 4;            // 33.6 MB
    (void)ws_size; (void)in_sizes; (void)n_in; (void)out_size;

    hipMemsetAsync(seg1, 0x80, (size_t)(NSEG1 + NSEG2) * SEG_U32 * 4, stream);

    {
        int nseg = NSEG1 + NSEG2;                   // 5632 waves
        k_prep<<<(nseg + 3) / 4, 256, 0, stream>>>(mat, seg1, seg2, hdr1, hdr2);
    }
    {
        dim3 g(BATCH / 64, IN_DIM / 64);            // 128 x 16
        k_xt<<<g, 256, 0, stream>>>(x, x_t);
    }
    {
        dim3 g(BATCH / BT, 8);                      // 64 x 8 = 512 blocks
        k_hid<<<g, 1024, 0, stream>>>(x_t, w, seg1, hdr1, hidden_t);
    }
    {
        dim3 g(BATCH / BT, 4);                      // 64 x 4 = 256 blocks
        k_out<<<g, 1024, 0, stream>>>(x_t, hidden_t, w, seg2, hdr2, partials);
    }
    {
        dim3 g(BATCH / 64, OUT_DIM / 16);           // 2048 blocks
        k_sum<<<g, 256, 0, stream>>>(partials, out);
    }
}

// Round 9
// 403.643 us; speedup vs baseline: 1.6142x; 1.2546x over previous
//
#include <hip/hip_runtime.h>
#include <hip/hip_bf16.h>
#include <stdint.h>

// Problem constants
#define BATCH   8192
#define IN_DIM  1024
#define N_HID   2048
#define OUT_DIM 256
#define SRC_DIM 3072

// Tiling
#define C     32                   // source columns per chunk
#define RB    16                   // rows per row-block (= rows per wave)
#define BT    128                  // batch per block (2 per lane: b, b+64)
#define S1_CH (IN_DIM / C)         // 32
#define S1_RB (N_HID / RB)         // 128
#define S2_CH (SRC_DIM / C)        // 96
#define S2_RB (OUT_DIM / RB)       // 16
#define NSEG1 (S1_RB * S1_CH)      // 4096
#define NSEG2 (S2_RB * S2_CH)      // 1536
#define ZSLOT 128                  // A-tile zero page (pad byte 0x80)

// Segment format v3 (stride 128 u32 = 512 B):
//   u32[0..7]   plane-0: row r -> u16 at byte 2r (2 slot bytes, pad 0x80)
//   7 overflow planes p=1..7 at u32 8+17(p-1):
//     [0] = 16-bit row mask (rows with n > 2+4(p-1))
//     [1+r] = 4 slot bytes for row r (pad 0x80)
//   hdr array: W = total planes (1 + ceil(max(n-2)/4)), wave-uniform.
// At lambda=1.6 edges/row-chunk: plane-0 is 64% real slots, ~3.5/16 rows
// overflow. All record/mask loads wave-uniform -> scalar path.
#define SEG_U32 128

// MEASURED MODEL (R3..R8): residency tracks register footprint, not LDS;
// the structural fix is ONE 1024-thr block = 16 waves sharing a 33 KB
// A-tile (4 waves/SIMD guaranteed). R8 counters: VALU-busy 197us of 298,
// LDS ~20M ops, 60% of slot work is padding -> v3 format cuts slots 28%.

// ---------------------------------------------------------------------------
__global__ void k_prep(const int* __restrict__ mat,
                       uint32_t* __restrict__ seg1, uint32_t* __restrict__ seg2,
                       uint32_t* __restrict__ hdr1, uint32_t* __restrict__ hdr2) {
    int wid  = (blockIdx.x * blockDim.x + threadIdx.x) >> 6;
    int lane = threadIdx.x & 63;
    if (wid >= NSEG1 + NSEG2) return;

    int row0, col0;
    uint32_t *seg, *hdr;
    if (wid < NSEG1) {
        int rb = wid / S1_CH, ch = wid % S1_CH;
        row0 = rb * RB;          col0 = ch * C;
        seg = seg1 + (size_t)wid * SEG_U32;  hdr = hdr1 + wid;
    } else {
        int s  = wid - NSEG1;
        int rb = s / S2_CH, ch = s % S2_CH;
        row0 = N_HID + rb * RB;  col0 = ch * C;
        seg = seg2 + (size_t)s * SEG_U32;    hdr = hdr2 + s;
    }

    int n = 0;
    if (lane < RB) {
        const int* mrow = mat + (size_t)(row0 + lane) * SRC_DIM + col0;
        uint8_t* sb = (uint8_t*)seg;
        for (int c = 0; c < C; c++) {
            int code = mrow[c];
            if (code != 0) {
                uint8_t slot = (uint8_t)((code - 1) * C + c);
                if (n < 2) {
                    sb[2 * lane + n] = slot;               // plane-0 u16
                } else {
                    int j = n - 2;
                    sb[(size_t)(8 + 17 * (j >> 2) + 1 + lane) * 4 + (j & 3)] = slot;
                }
                n++;
            }
        }
    }
    int m = n;
    #pragma unroll
    for (int d = 1; d < 64; d <<= 1) m = max(m, __shfl_xor(m, d));
    uint32_t Wv = (m <= 2) ? 1u : 1u + (uint32_t)((m - 2 + 3) >> 2);

    for (uint32_t p = 1; p < Wv; p++) {
        unsigned long long b = __ballot(n > 2 + 4 * (int)(p - 1));
        if (lane == 0) seg[8 + 17 * (p - 1)] = (uint32_t)(b & 0xFFFFu);
    }
    if (lane == 0) *hdr = Wv;
}

// ---------------------------------------------------------------------------
// k_xt: transpose x[8192][1024] -> x_t[1024][8192] (fp32), 64x64 LDS tiles.
// ---------------------------------------------------------------------------
__global__ __launch_bounds__(256) void k_xt(const float* __restrict__ x,
                                            float* __restrict__ x_t) {
    __shared__ float t[64][65];
    const int b0 = blockIdx.x * 64, c0 = blockIdx.y * 64;
    {
        int r  = threadIdx.x >> 4;
        int cq = (threadIdx.x & 15) * 4;
        #pragma unroll
        for (int k = 0; k < 4; k++) {
            int rr = r + 16 * k;
            float4 v = *(const float4*)&x[(size_t)(b0 + rr) * IN_DIM + c0 + cq];
            t[rr][cq + 0] = v.x; t[rr][cq + 1] = v.y;
            t[rr][cq + 2] = v.z; t[rr][cq + 3] = v.w;
        }
    }
    __syncthreads();
    {
        int bq  = (threadIdx.x & 15) * 4;
        int cc0 = threadIdx.x >> 4;
        #pragma unroll
        for (int k = 0; k < 4; k++) {
            int cc = cc0 + 16 * k;
            float4 v;
            v.x = t[bq + 0][cc]; v.y = t[bq + 1][cc];
            v.z = t[bq + 2][cc]; v.w = t[bq + 3][cc];
            *(float4*)&x_t[(size_t)(c0 + cc) * BATCH + b0 + bq] = v;
        }
    }
}

// pack two floats as bf16 pair: low16 = batch b, high16 = batch b+64
__device__ __forceinline__ uint32_t pack2(float a, float b) {
    __hip_bfloat162 h = __float22bfloat162_rn(make_float2(a, b));
    union { __hip_bfloat162 h2; uint32_t u; } u;
    u.h2 = h;
    return u.u;
}

// A-tile: As[slot*64 + lane] u32 = bf16 pair; slot = t*32+c; slot 128 = zeros.
__device__ __forceinline__ void write_acts2(uint32_t* As, int c, int lane,
                                            float va, float vb) {
    As[(0 * C + c) * 64 + lane] = pack2(va, vb);
    As[(1 * C + c) * 64 + lane] = pack2(fmaxf(va, 0.0f), fmaxf(vb, 0.0f));
    float ta = 1.0f - 2.0f / (__expf(2.0f * va) + 1.0f);
    float tb = 1.0f - 2.0f / (__expf(2.0f * vb) + 1.0f);
    As[(2 * C + c) * 64 + lane] = pack2(ta, tb);
    float sa = 1.0f / (1.0f + __expf(-va));
    float sb = 1.0f / (1.0f + __expf(-vb));
    As[(3 * C + c) * 64 + lane] = pack2(sa, sb);
}

// acc element: float2 (x = batch b, y = batch b+64) -> invites v_pk_add_f32
#define SLOT_ACC(AR, S)                                                        \
    {                                                                          \
        uint32_t q = As[(S) * 64 + lane];                                      \
        (AR).x += __uint_as_float(q << 16);                                    \
        (AR).y += __uint_as_float(q & 0xFFFF0000u);                            \
    }

#define EDGE_PLANES(SEGBASE, WVAL)                                             \
    {                                                                          \
        const uint32_t* sp_ = (SEGBASE);                                       \
        _Pragma("unroll")                                                      \
        for (int i = 0; i < 8; i++) {                                          \
            uint32_t g = sp_[i];                                               \
            SLOT_ACC(acc[2 * i],     g & 255u)                                 \
            SLOT_ACC(acc[2 * i],     (g >> 8) & 255u)                          \
            SLOT_ACC(acc[2 * i + 1], (g >> 16) & 255u)                         \
            SLOT_ACC(acc[2 * i + 1], g >> 24)                                  \
        }                                                                      \
        for (uint32_t p = 1; p < (WVAL); p++) {                                \
            const uint32_t* pp_ = sp_ + 8 + 17 * (p - 1);                      \
            uint32_t mask = pp_[0];                                            \
            _Pragma("unroll")                                                  \
            for (int r = 0; r < RB; r++) {                                     \
                if (mask & (1u << r)) {                                        \
                    uint32_t g = pp_[1 + r];                                   \
                    SLOT_ACC(acc[r], g & 255u)                                 \
                    SLOT_ACC(acc[r], (g >> 8) & 255u)                          \
                    SLOT_ACC(acc[r], (g >> 16) & 255u)                         \
                    SLOT_ACC(acc[r], g >> 24)                                  \
                }                                                              \
            }                                                                  \
        }                                                                      \
    }

// ---------------------------------------------------------------------------
// Stage 1: 1024 thr = 16 waves x 16 rows = 256 rows; lane pair = (b, b+64).
// Grid (64 tiles, 8 row splits). LDS = A-tile only (33.25 KB), 16 waves/CU.
// ---------------------------------------------------------------------------
__global__ __launch_bounds__(1024, 1) void k_hid(const float* __restrict__ x_t,
                                                 const float* __restrict__ wp,
                                                 const uint32_t* __restrict__ seg1,
                                                 const uint32_t* __restrict__ hdr1,
                                                 __hip_bfloat16* __restrict__ hidden_t) {
    __shared__ uint32_t As[(4 * C + 1) * 64];   // 33.25 KB

    const float w  = wp[0];
    const int tile = blockIdx.x;                // 0..63
    const int lane = threadIdx.x & 63;
    const int wv   = __builtin_amdgcn_readfirstlane(threadIdx.x >> 6); // 0..15
    const int rb   = blockIdx.y * 16 + wv;      // row-block 0..127
    const int bA   = tile * BT + lane;
    const int bB   = bA + 64;

    if (threadIdx.x < 64) As[ZSLOT * 64 + threadIdx.x] = 0u;

    float2 acc[RB];
    #pragma unroll
    for (int r = 0; r < RB; r++) acc[r] = make_float2(0.0f, 0.0f);

    // prefetch chunk 0: each wave owns 2 columns
    float va[2], vb[2];
    #pragma unroll
    for (int j = 0; j < 2; j++) {
        int gcol = wv * 2 + j;
        va[j] = w * x_t[(size_t)gcol * BATCH + bA];
        vb[j] = w * x_t[(size_t)gcol * BATCH + bB];
    }

    #pragma unroll 1
    for (int ch = 0; ch < S1_CH; ch++) {
        __syncthreads();                        // edge-phase(ch-1) done
        #pragma unroll
        for (int j = 0; j < 2; j++)
            write_acts2(As, wv * 2 + j, lane, va[j], vb[j]);
        __syncthreads();                        // acts visible
        if (ch + 1 < S1_CH) {                   // prefetch next chunk
            #pragma unroll
            for (int j = 0; j < 2; j++) {
                int gcol = (ch + 1) * C + wv * 2 + j;
                va[j] = w * x_t[(size_t)gcol * BATCH + bA];
                vb[j] = w * x_t[(size_t)gcol * BATCH + bB];
            }
        }
        int sidx = rb * S1_CH + ch;
        uint32_t W = hdr1[sidx];
        EDGE_PLANES(seg1 + (size_t)sidx * SEG_U32, W)
    }

    const int row0 = rb * RB;
    #pragma unroll
    for (int r = 0; r < RB; r++) {
        hidden_t[(size_t)(row0 + r) * BATCH + bA] = __float2bfloat16(acc[r].x);
        hidden_t[(size_t)(row0 + r) * BATCH + bB] = __float2bfloat16(acc[r].y);
    }
}

// ---------------------------------------------------------------------------
// Stage 2: 1024 thr = 16 waves x 16 rows = ALL 256 out rows.
// Grid (64 tiles, 4 chunk groups of 24). Partials [cg][r][b].
// ---------------------------------------------------------------------------
__global__ __launch_bounds__(1024, 1) void k_out(const float* __restrict__ x_t,
                                                 const __hip_bfloat16* __restrict__ hidden_t,
                                                 const float* __restrict__ wp,
                                                 const uint32_t* __restrict__ seg2,
                                                 const uint32_t* __restrict__ hdr2,
                                                 float* __restrict__ partials) {
    __shared__ uint32_t As[(4 * C + 1) * 64];

    const float w  = wp[0];
    const int tile = blockIdx.x;                // 0..63
    const int cg   = blockIdx.y;                // 0..3
    const int lane = threadIdx.x & 63;
    const int wv   = __builtin_amdgcn_readfirstlane(threadIdx.x >> 6); // 0..15
    const int bA   = tile * BT + lane;
    const int bB   = bA + 64;

    if (threadIdx.x < 64) As[ZSLOT * 64 + threadIdx.x] = 0u;

    float2 acc[RB];
    #pragma unroll
    for (int r = 0; r < RB; r++) acc[r] = make_float2(0.0f, 0.0f);

    float va[2], vb[2];
    #pragma unroll
    for (int j = 0; j < 2; j++) {
        int gcol = (cg * 24) * C + wv * 2 + j;
        if (gcol < IN_DIM) {
            va[j] = w * x_t[(size_t)gcol * BATCH + bA];
            vb[j] = w * x_t[(size_t)gcol * BATCH + bB];
        } else {
            va[j] = w * __bfloat162float(hidden_t[(size_t)(gcol - IN_DIM) * BATCH + bA]);
            vb[j] = w * __bfloat162float(hidden_t[(size_t)(gcol - IN_DIM) * BATCH + bB]);
        }
    }

    #pragma unroll 1
    for (int cj = 0; cj < 24; cj++) {
        int ch = cg * 24 + cj;
        __syncthreads();
        #pragma unroll
        for (int j = 0; j < 2; j++)
            write_acts2(As, wv * 2 + j, lane, va[j], vb[j]);
        __syncthreads();
        if (cj + 1 < 24) {
            #pragma unroll
            for (int j = 0; j < 2; j++) {
                int gcol = (ch + 1) * C + wv * 2 + j;
                if (gcol < IN_DIM) {
                    va[j] = w * x_t[(size_t)gcol * BATCH + bA];
                    vb[j] = w * x_t[(size_t)gcol * BATCH + bB];
                } else {
                    va[j] = w * __bfloat162float(hidden_t[(size_t)(gcol - IN_DIM) * BATCH + bA]);
                    vb[j] = w * __bfloat162float(hidden_t[(size_t)(gcol - IN_DIM) * BATCH + bB]);
                }
            }
        }
        int sidx = wv * S2_CH + ch;              // wv = row-block 0..15
        uint32_t W = hdr2[sidx];
        EDGE_PLANES(seg2 + (size_t)sidx * SEG_U32, W)
    }

    #pragma unroll
    for (int r = 0; r < RB; r++) {
        size_t base = ((size_t)cg * OUT_DIM + wv * RB + r) * BATCH;
        partials[base + bA] = acc[r].x;
        partials[base + bB] = acc[r].y;
    }
}

// ---------------------------------------------------------------------------
// k_sum: reduce 4 partial planes + transpose [r][b] -> out[b][r] (float4).
// ---------------------------------------------------------------------------
__global__ __launch_bounds__(256) void k_sum(const float* __restrict__ partials,
                                             float* __restrict__ out) {
    __shared__ float t[16][65];
    const int b0 = blockIdx.x * 64, r0 = blockIdx.y * 16;
    const int lane = threadIdx.x & 63;
    const int g4   = threadIdx.x >> 6;

    #pragma unroll
    for (int k = 0; k < 4; k++) {
        int rr = g4 * 4 + k;
        float s = 0.0f;
        #pragma unroll
        for (int cg = 0; cg < 4; cg++)
            s += partials[((size_t)cg * OUT_DIM + r0 + rr) * BATCH + b0 + lane];
        t[rr][lane] = s;
    }
    __syncthreads();
    int bb = threadIdx.x >> 2, rq = threadIdx.x & 3;
    float4 v;
    v.x = t[rq * 4 + 0][bb];
    v.y = t[rq * 4 + 1][bb];
    v.z = t[rq * 4 + 2][bb];
    v.w = t[rq * 4 + 3][bb];
    *(float4*)&out[(size_t)(b0 + bb) * OUT_DIM + r0 + rq * 4] = v;
}

// ---------------------------------------------------------------------------
extern "C" void kernel_launch(void* const* d_in, const int* in_sizes, int n_in,
                              void* d_out, int out_size, void* d_ws, size_t ws_size,
                              hipStream_t stream) {
    const float* x   = (const float*)d_in[0];
    const float* w   = (const float*)d_in[1];
    const int*   mat = (const int*)d_in[2];
    float* out = (float*)d_out;

    uint8_t* ws = (uint8_t*)d_ws;
    size_t off = 0;
    __hip_bfloat16* hidden_t = (__hip_bfloat16*)(ws + off); off += (size_t)BATCH * N_HID * 2;  // 33.6 MB
    float* x_t = (float*)(ws + off);        off += (size_t)IN_DIM * BATCH * 4;                 // 33.6 MB
    uint32_t* seg1 = (uint32_t*)(ws + off); off += (size_t)NSEG1 * SEG_U32 * 4;                //  2.10 MB
    uint32_t* seg2 = (uint32_t*)(ws + off); off += (size_t)NSEG2 * SEG_U32 * 4;                //  0.79 MB
    uint32_t* hdr1 = (uint32_t*)(ws + off); off += (size_t)NSEG1 * 4;
    uint32_t* hdr2 = (uint32_t*)(ws + off); off += (size_t)NSEG2 * 4;
    float* partials = (float*)(ws + off);   off += (size_t)4 * OUT_DIM * BATCH * 4;            // 33.6 MB
    (void)ws_size; (void)in_sizes; (void)n_in; (void)out_size;

    hipMemsetAsync(seg1, 0x80, (size_t)(NSEG1 + NSEG2) * SEG_U32 * 4, stream);

    {
        int nseg = NSEG1 + NSEG2;                   // 5632 waves
        k_prep<<<(nseg + 3) / 4, 256, 0, stream>>>(mat, seg1, seg2, hdr1, hdr2);
    }
    {
        dim3 g(BATCH / 64, IN_DIM / 64);            // 128 x 16
        k_xt<<<g, 256, 0, stream>>>(x, x_t);
    }
    {
        dim3 g(BATCH / BT, 8);                      // 64 x 8 = 512 blocks
        k_hid<<<g, 1024, 0, stream>>>(x_t, w, seg1, hdr1, hidden_t);
    }
    {
        dim3 g(BATCH / BT, 4);                      // 64 x 4 = 256 blocks
        k_out<<<g, 1024, 0, stream>>>(x_t, hidden_t, w, seg2, hdr2, partials);
    }
    {
        dim3 g(BATCH / 64, OUT_DIM / 16);           // 2048 blocks
        k_sum<<<g, 256, 0, stream>>>(partials, out);
    }
}